// Round 16
// baseline (50.245 us; speedup 1.0000x reference)
//
#include <hip/hip_runtime.h>

typedef float f32x4 __attribute__((ext_vector_type(4)));

// ---------- cross-lane helpers (compile-time patterns) ----------
template<int CTRL>
__device__ __forceinline__ float dpp1(float x) {
    // DPP move, old = 1.0f (multiplicative identity), bound_ctrl=false.
    return __int_as_float(__builtin_amdgcn_update_dpp(
        0x3f800000, __float_as_int(x), CTRL, 0xF, 0xF, false));
}
template<int CTRL>
__device__ __forceinline__ float dpp0(float x) {
    // DPP move, additive identity: bound_ctrl=true -> out-of-row reads 0.
    return __int_as_float(__builtin_amdgcn_update_dpp(
        0, __float_as_int(x), CTRL, 0xF, 0xF, true));
}
template<int PAT>
__device__ __forceinline__ float swz(float x) {
    return __int_as_float(__builtin_amdgcn_ds_swizzle(__float_as_int(x), PAT));
}

__device__ __forceinline__ void ntst4(float* p, float x, float y, float z, float w) {
    f32x4 v = {x, y, z, w};
    __builtin_nontemporal_store(v, (f32x4*)p);
}
__device__ __forceinline__ float sel3(int m, float x, float y, float z) {
    return m == 0 ? x : (m == 1 ? y : z);
}

// Kernel 1: gap-filled segment bounds. After this, seg_se[2r],[2r+1] are valid
// for EVERY r in [0,R): absent rays get (p,p) at the enclosing transition.
__global__ __launch_bounds__(256) void seg_bounds_kernel(
    const int* __restrict__ ray_id, int n, int R, int* __restrict__ seg_se)
{
    const int t = blockIdx.x * blockDim.x + threadIdx.x;
    const int a = t * 4;
    if (a >= n) return;            // n % 4 == 0
    const int4 rv = *(const int4*)(ray_id + a);

    // transition (u -> v) at position p: close u, fill gap ids empty, open v
#define TRANS(u, v, p) do {                                                   \
        if ((u) >= 0) seg_se[2 * (u) + 1] = (p);                              \
        for (int id_ = (u) + 1; id_ < (v); ++id_) {                           \
            seg_se[2 * id_] = (p); seg_se[2 * id_ + 1] = (p); }               \
        if ((v) < R) seg_se[2 * (v)] = (p); } while (0)

    if (a == 0) TRANS(-1, rv.x, 0);
    if (rv.y != rv.x) TRANS(rv.x, rv.y, a + 1);
    if (rv.z != rv.y) TRANS(rv.y, rv.z, a + 2);
    if (rv.w != rv.z) TRANS(rv.z, rv.w, a + 3);
    if (a + 4 == n) {
        TRANS(rv.w, R, n);
    } else {
        const int nx = ray_id[a + 4];
        if (nx != rv.w) TRANS(rv.w, nx, a + 4);
    }
#undef TRANS
}

// Kernel 2: 8 lanes per ray (32-slot tiles matching the 32-sample mean),
// 4 samples per lane, 8 rays/wave, 8 waves/block (64 rays, 512 threads).
// Fused scan + segment sums + phase-aligned sps broadcast.
__global__ __launch_bounds__(512) void ray_kernel(
    const float* __restrict__ alpha,
    const float* __restrict__ values3d,
    const float* __restrict__ values1d,
    const float* __restrict__ weights,
    const float* __restrict__ sample_values,
    const int*   __restrict__ seg_se,
    float* __restrict__ out_T,    // [N]
    float* __restrict__ out_bg,   // [R]
    float* __restrict__ out_i3,   // [R,3]
    float* __restrict__ out_i1,   // [R]
    float* __restrict__ out_spr,  // [R,3]
    float* __restrict__ out_sps,  // [N,3]
    int R)
{
    __shared__ float prr[64][9];   // per-ray {bg, i1, i3xyz, spr xyz}; padded

    const int lane = threadIdx.x & 63;
    const int wid  = threadIdx.x >> 6;       // wave 0..7
    const int jj   = lane & 7;               // lane within 8-lane group
    const int g    = lane >> 3;              // group (ray slot in wave) 0..7
    const int slot = wid * 8 + g;            // ray slot in block 0..63
    const int r0   = blockIdx.x * 64;        // block's first ray
    const int r    = r0 + slot;
    const bool ray_ok = (r < R);
    const int rc = ray_ok ? r : 0;

    const int2 se = ((const int2*)seg_se)[rc];   // one 8B load, trusted
    int s0 = se.x, s1 = se.y;
    if (!ray_ok) { s0 = 0; s1 = 0; }

    float c = 1.0f;                          // running product carry
    float i3x = 0.f, i3y = 0.f, i3z = 0.f, i1 = 0.f;
    float sx = 0.f, sy = 0.f, sz = 0.f;

    const int base0 = s0 & ~3;               // align tile grid to float4

    for (int base = base0; base < s1; base += 32) {
        const int a = base + 4 * jj;         // this lane's aligned 4-sample slot
        const bool tile_ok = (a < s1);
        const int  al = tile_ok ? a : base0; // clamp to valid in-segment addr

        // ---- issue loads at iteration top ----
        const f32x4 av  = *(const f32x4*)(alpha + al);
        const f32x4 wv  = *(const f32x4*)(weights + al);
        const f32x4 v1v = *(const f32x4*)(values1d + al);
        const f32x4 b0  = *(const f32x4*)(values3d + 3 * al);
        const f32x4 b1  = *(const f32x4*)(values3d + 3 * al + 4);
        const f32x4 b2  = *(const f32x4*)(values3d + 3 * al + 8);
        const f32x4 q0  = *(const f32x4*)(sample_values + 3 * al);
        const f32x4 q1  = *(const f32x4*)(sample_values + 3 * al + 4);
        const f32x4 q2  = *(const f32x4*)(sample_values + 3 * al + 8);

        // element ownership masks
        const bool w0 = tile_ok & (a + 0 >= s0);
        const bool w1 = tile_ok & (a + 1 >= s0) & (a + 1 < s1);
        const bool w2 = tile_ok & (a + 2 >= s0) & (a + 2 < s1);
        const bool w3 = tile_ok & (a + 3 < s1);

        float o0 = fminf(fmaxf(1.0f - av.x, 1e-7f), 1.0f); if (!w0) o0 = 1.0f;
        float o1 = fminf(fmaxf(1.0f - av.y, 1e-7f), 1.0f); if (!w1) o1 = 1.0f;
        float o2 = fminf(fmaxf(1.0f - av.z, 1e-7f), 1.0f); if (!w2) o2 = 1.0f;
        float o3 = fminf(fmaxf(1.0f - av.w, 1e-7f), 1.0f); if (!w3) o3 = 1.0f;

        const float p01  = o0 * o1;
        const float p012 = p01 * o2;
        float p = p012 * o3;                 // lane-local product

        // inclusive multiplicative scan across the 8-lane group (predicated
        // DPP: sub-row crossings at lane 8 of each 16-row are masked)
        float u;
        u = dpp1<0x111>(p); p *= (jj >= 1) ? u : 1.0f;
        u = dpp1<0x112>(p); p *= (jj >= 2) ? u : 1.0f;
        u = dpp1<0x114>(p); p *= (jj >= 4) ? u : 1.0f;
        const float gincl = p;
        u = dpp1<0x111>(gincl);
        const float gexcl = (jj >= 1) ? u : 1.0f;   // lane jj=0 gets 1.0

        const float cg = c * gexcl;
        const float t0 = cg;
        const float t1 = cg * o0;
        const float t2 = cg * p01;
        const float t3 = cg * p012;

        // accumulate (masked)
        const float W0 = w0 ? wv.x : 0.f;
        const float W1 = w1 ? wv.y : 0.f;
        const float W2 = w2 ? wv.z : 0.f;
        const float W3 = w3 ? wv.w : 0.f;
        const float M0 = w0 ? 1.f : 0.f;
        const float M1 = w1 ? 1.f : 0.f;
        const float M2 = w2 ? 1.f : 0.f;
        const float M3 = w3 ? 1.f : 0.f;

        i1  += v1v.x * W0 + v1v.y * W1 + v1v.z * W2 + v1v.w * W3;
        i3x += b0.x * W0 + b0.w * W1 + b1.z * W2 + b2.y * W3;
        i3y += b0.y * W0 + b1.x * W1 + b1.w * W2 + b2.z * W3;
        i3z += b0.z * W0 + b1.y * W1 + b2.x * W2 + b2.w * W3;
        sx  += q0.x * M0 + q0.w * M1 + q1.z * M2 + q2.y * M3;
        sy  += q0.y * M0 + q1.x * M1 + q1.w * M2 + q2.z * M3;
        sz  += q0.z * M0 + q1.y * M1 + q2.x * M2 + q2.w * M3;

        // T stores: NT only on dense full-tile path (full cache lines)
        if (w0 & w1 & w2 & w3) {
            ntst4(out_T + a, t0, t1, t2, t3);
        } else {
            if (w0) out_T[a + 0] = t0;
            if (w1) out_T[a + 1] = t1;
            if (w2) out_T[a + 2] = t2;
            if (w3) out_T[a + 3] = t3;
        }

        // carry: chunk total lives in lane 7 of the group
        c *= swz<0x00F8>(gincl);             // bcast group-lane-7 ((lane&0x18)|7)
    }

    // 8-lane reductions (predicated DPP funnels; total in lane 7)
#define FUNNEL8(v) do { \
        float u_; \
        u_ = dpp0<0x111>(v); v += (jj >= 1) ? u_ : 0.f; \
        u_ = dpp0<0x112>(v); v += (jj >= 2) ? u_ : 0.f; \
        u_ = dpp0<0x114>(v); v += (jj >= 4) ? u_ : 0.f; } while (0)

    FUNNEL8(sx); FUNNEL8(sy); FUNNEL8(sz);
    sx = swz<0x00F8>(sx);
    sy = swz<0x00F8>(sy);
    sz = swz<0x00F8>(sz);

    // pass 2: phase-aligned contiguous sps broadcast (register-only inputs,
    // before the barrier). Head/tail by 6 lanes, one predicated store each.
    {
        const int F0 = 3 * s0, F1 = 3 * s1;
        const int H1 = min((F0 + 3) & ~3, F1);   // head end (first aligned pos)
        const int A1 = max(F1 & ~3, H1);         // full-chunk end
        if (jj < 6) {
            const int f = (jj < 3) ? (F0 + jj) : (A1 + jj - 3);
            const bool doit = (jj < 3) ? (f < H1) : (f < F1);
            if (doit) out_sps[f] = sel3(f % 3, sx, sy, sz);
        }
        for (int f = H1 + 4 * jj; f < A1; f += 32) {
            const int m = f % 3;
            const float v0 = sel3(m, sx, sy, sz);
            const float v1 = sel3(m == 2 ? 0 : m + 1, sx, sy, sz);
            const float v2 = sel3(m == 0 ? 2 : m - 1, sx, sy, sz);
            ntst4(out_sps + f, v0, v1, v2, v0);
        }
    }

    // i3/i1 reduction + LDS staging (after pass 2; only epilogue needs it)
    FUNNEL8(i3x); FUNNEL8(i3y); FUNNEL8(i3z); FUNNEL8(i1);
#undef FUNNEL8
    if (jj == 7) {
        prr[slot][0] = c;
        prr[slot][1] = i1;
        prr[slot][2] = i3x; prr[slot][3] = i3y; prr[slot][4] = i3z;
        prr[slot][5] = sx;  prr[slot][6] = sy;  prr[slot][7] = sz;
    }
    __syncthreads();

    // coalesced per-ray output stores: 512 threads, 1 float each
    {
        const int t = threadIdx.x;
        float val; float* addr; int ridx;
        if (t < 64)       { ridx = t;                 val = prr[ridx][0];          addr = out_bg  + r0 + t; }
        else if (t < 128) { ridx = t - 64;            val = prr[ridx][1];          addr = out_i1  + r0 + ridx; }
        else if (t < 320) { int s = t - 128; ridx = s / 3; val = prr[ridx][2 + s % 3]; addr = out_i3  + 3 * r0 + s; }
        else              { int s = t - 320; ridx = s / 3; val = prr[ridx][5 + s % 3]; addr = out_spr + 3 * r0 + s; }
        if (r0 + ridx < R) *addr = val;
    }
}

extern "C" void kernel_launch(void* const* d_in, const int* in_sizes, int n_in,
                              void* d_out, int out_size, void* d_ws, size_t ws_size,
                              hipStream_t stream) {
    const float* alpha = (const float*)d_in[0];
    const float* v3    = (const float*)d_in[1];
    const float* v1    = (const float*)d_in[2];
    const float* w     = (const float*)d_in[3];
    const float* sv    = (const float*)d_in[4];
    const int*   rid   = (const int*)d_in[5];

    int N = in_sizes[0];
    int R = (out_size - 4 * N) / 8;  // out = N + R + 3R + R + 3R + 3N

    int* seg_se = (int*)d_ws;        // [R][2]; fully written by seg_bounds (gap-filled)

    float* out     = (float*)d_out;
    float* out_T   = out;
    float* out_bg  = out + N;
    float* out_i3  = out_bg + R;
    float* out_i1  = out_i3 + 3 * (size_t)R;
    float* out_spr = out_i1 + R;
    float* out_sps = out_spr + 3 * (size_t)R;

    const int nquad = N / 4;
    seg_bounds_kernel<<<(nquad + 255) / 256, 256, 0, stream>>>(rid, N, R, seg_se);

    // 8 waves/block, 8 rays/wave -> 64 rays per block
    int blocks = (R + 63) / 64;
    ray_kernel<<<blocks, 512, 0, stream>>>(alpha, v3, v1, w, sv, seg_se,
                                           out_T, out_bg, out_i3, out_i1, out_spr,
                                           out_sps, R);
}

// Round 17
// 45.209 us; speedup vs baseline: 1.1114x; 1.1114x over previous
//
#include <hip/hip_runtime.h>

typedef float f32x4 __attribute__((ext_vector_type(4)));

// ---------- cross-lane helpers (compile-time patterns) ----------
template<int CTRL>
__device__ __forceinline__ float dpp1(float x) {
    // DPP move, old = 1.0f (multiplicative identity), bound_ctrl=false.
    return __int_as_float(__builtin_amdgcn_update_dpp(
        0x3f800000, __float_as_int(x), CTRL, 0xF, 0xF, false));
}
template<int CTRL>
__device__ __forceinline__ float dpp0(float x) {
    // DPP move, additive identity: bound_ctrl=true -> out-of-row reads 0.
    return __int_as_float(__builtin_amdgcn_update_dpp(
        0, __float_as_int(x), CTRL, 0xF, 0xF, true));
}
template<int PAT>
__device__ __forceinline__ float swz(float x) {
    return __int_as_float(__builtin_amdgcn_ds_swizzle(__float_as_int(x), PAT));
}
// row-wise (16-lane) reduction; total lands in lane 15 of each row
#define FUNNEL16(v) do { \
    v += dpp0<0x111>(v); \
    v += dpp0<0x112>(v); \
    v += dpp0<0x114>(v); \
    v += dpp0<0x118>(v); } while (0)

__device__ __forceinline__ void ntst4(float* p, float x, float y, float z, float w) {
    f32x4 v = {x, y, z, w};
    __builtin_nontemporal_store(v, (f32x4*)p);
}
__device__ __forceinline__ float sel3(int m, float x, float y, float z) {
    return m == 0 ? x : (m == 1 ? y : z);
}

// Kernel 1: gap-filled segment bounds. After this, seg_se[2r],[2r+1] are valid
// for EVERY r in [0,R): absent rays get (p,p) at the enclosing transition.
__global__ __launch_bounds__(256) void seg_bounds_kernel(
    const int* __restrict__ ray_id, int n, int R, int* __restrict__ seg_se)
{
    const int t = blockIdx.x * blockDim.x + threadIdx.x;
    const int a = t * 4;
    if (a >= n) return;            // n % 4 == 0
    const int4 rv = *(const int4*)(ray_id + a);

    // transition (u -> v) at position p: close u, fill gap ids empty, open v
#define TRANS(u, v, p) do {                                                   \
        if ((u) >= 0) seg_se[2 * (u) + 1] = (p);                              \
        for (int id_ = (u) + 1; id_ < (v); ++id_) {                           \
            seg_se[2 * id_] = (p); seg_se[2 * id_ + 1] = (p); }               \
        if ((v) < R) seg_se[2 * (v)] = (p); } while (0)

    if (a == 0) TRANS(-1, rv.x, 0);
    if (rv.y != rv.x) TRANS(rv.x, rv.y, a + 1);
    if (rv.z != rv.y) TRANS(rv.y, rv.z, a + 2);
    if (rv.w != rv.z) TRANS(rv.z, rv.w, a + 3);
    if (a + 4 == n) {
        TRANS(rv.w, R, n);
    } else {
        const int nx = ray_id[a + 4];
        if (nx != rv.w) TRANS(rv.w, nx, a + 4);
    }
#undef TRANS
}

// Kernel 2: 16 lanes per ray, 4 samples per lane, 4 rays/wave, 8 waves/block
// (32 rays, 512 threads). Fused scan + segment sums + phase-aligned sps
// broadcast. Per-ray outputs staged in LDS, stored coalesced.
__global__ __launch_bounds__(512) void ray_kernel(
    const float* __restrict__ alpha,
    const float* __restrict__ values3d,
    const float* __restrict__ values1d,
    const float* __restrict__ weights,
    const float* __restrict__ sample_values,
    const int*   __restrict__ seg_se,
    float* __restrict__ out_T,    // [N]
    float* __restrict__ out_bg,   // [R]
    float* __restrict__ out_i3,   // [R,3]
    float* __restrict__ out_i1,   // [R]
    float* __restrict__ out_spr,  // [R,3]
    float* __restrict__ out_sps,  // [N,3]
    int R)
{
    __shared__ float prr[32][9];   // per-ray {bg, i1, i3xyz, spr xyz}; padded

    const int lane = threadIdx.x & 63;
    const int wid  = threadIdx.x >> 6;       // wave 0..7
    const int j    = lane & 15;              // lane within 16-lane group
    const int g    = lane >> 4;              // group (ray slot in wave) 0..3
    const int slot = wid * 4 + g;            // ray slot in block 0..31
    const int r0   = blockIdx.x * 32;        // block's first ray
    const int r    = r0 + slot;
    const bool ray_ok = (r < R);
    const int rc = ray_ok ? r : 0;

    const int2 se = ((const int2*)seg_se)[rc];   // one 8B load, trusted
    int s0 = se.x, s1 = se.y;
    if (!ray_ok) { s0 = 0; s1 = 0; }

    float c = 1.0f;                          // running product carry
    float i3x = 0.f, i3y = 0.f, i3z = 0.f, i1 = 0.f;
    float sx = 0.f, sy = 0.f, sz = 0.f;

    const int base0 = s0 & ~3;               // align tile grid to float4

    for (int base = base0; base < s1; base += 64) {
        const int a = base + 4 * j;          // this lane's aligned 4-sample slot
        const bool tile_ok = (a < s1);
        const int  al = tile_ok ? a : base0; // clamp to valid in-segment addr

        // ---- issue loads at iteration top ----
        const f32x4 av  = *(const f32x4*)(alpha + al);
        const f32x4 wv  = *(const f32x4*)(weights + al);
        const f32x4 v1v = *(const f32x4*)(values1d + al);
        const f32x4 b0  = *(const f32x4*)(values3d + 3 * al);
        const f32x4 b1  = *(const f32x4*)(values3d + 3 * al + 4);
        const f32x4 b2  = *(const f32x4*)(values3d + 3 * al + 8);
        const f32x4 q0  = *(const f32x4*)(sample_values + 3 * al);
        const f32x4 q1  = *(const f32x4*)(sample_values + 3 * al + 4);
        const f32x4 q2  = *(const f32x4*)(sample_values + 3 * al + 8);

        // element ownership masks
        const bool w0 = tile_ok & (a + 0 >= s0);
        const bool w1 = tile_ok & (a + 1 >= s0) & (a + 1 < s1);
        const bool w2 = tile_ok & (a + 2 >= s0) & (a + 2 < s1);
        const bool w3 = tile_ok & (a + 3 < s1);

        float o0 = fminf(fmaxf(1.0f - av.x, 1e-7f), 1.0f); if (!w0) o0 = 1.0f;
        float o1 = fminf(fmaxf(1.0f - av.y, 1e-7f), 1.0f); if (!w1) o1 = 1.0f;
        float o2 = fminf(fmaxf(1.0f - av.z, 1e-7f), 1.0f); if (!w2) o2 = 1.0f;
        float o3 = fminf(fmaxf(1.0f - av.w, 1e-7f), 1.0f); if (!w3) o3 = 1.0f;

        const float p01  = o0 * o1;
        const float p012 = p01 * o2;
        float p = p012 * o3;                 // lane-local product

        // inclusive multiplicative scan across the 16-lane row (DPP)
        p *= dpp1<0x111>(p);                 // row_shr:1
        p *= dpp1<0x112>(p);                 // row_shr:2
        p *= dpp1<0x114>(p);                 // row_shr:4
        p *= dpp1<0x118>(p);                 // row_shr:8
        const float gincl = p;
        const float gexcl = dpp1<0x111>(gincl);  // lane j=0 gets 1.0

        const float cg = c * gexcl;
        const float t0 = cg;
        const float t1 = cg * o0;
        const float t2 = cg * p01;
        const float t3 = cg * p012;

        // accumulate (masked)
        const float W0 = w0 ? wv.x : 0.f;
        const float W1 = w1 ? wv.y : 0.f;
        const float W2 = w2 ? wv.z : 0.f;
        const float W3 = w3 ? wv.w : 0.f;
        const float M0 = w0 ? 1.f : 0.f;
        const float M1 = w1 ? 1.f : 0.f;
        const float M2 = w2 ? 1.f : 0.f;
        const float M3 = w3 ? 1.f : 0.f;

        i1  += v1v.x * W0 + v1v.y * W1 + v1v.z * W2 + v1v.w * W3;
        i3x += b0.x * W0 + b0.w * W1 + b1.z * W2 + b2.y * W3;
        i3y += b0.y * W0 + b1.x * W1 + b1.w * W2 + b2.z * W3;
        i3z += b0.z * W0 + b1.y * W1 + b2.x * W2 + b2.w * W3;
        sx  += q0.x * M0 + q0.w * M1 + q1.z * M2 + q2.y * M3;
        sy  += q0.y * M0 + q1.x * M1 + q1.w * M2 + q2.z * M3;
        sz  += q0.z * M0 + q1.y * M1 + q2.x * M2 + q2.w * M3;

        // T stores: NT only on dense full-tile path (full cache lines)
        if (w0 & w1 & w2 & w3) {
            ntst4(out_T + a, t0, t1, t2, t3);
        } else {
            if (w0) out_T[a + 0] = t0;
            if (w1) out_T[a + 1] = t1;
            if (w2) out_T[a + 2] = t2;
            if (w3) out_T[a + 3] = t3;
        }

        // carry: chunk total lives in lane 15 of the group
        c *= swz<0x1F0>(gincl);              // bcast group-lane-15
    }

    // s* channels first: reduce + broadcast, so pass-2 stores can issue ASAP
    FUNNEL16(sx);  FUNNEL16(sy);  FUNNEL16(sz);
    sx = swz<0x1F0>(sx);
    sy = swz<0x1F0>(sy);
    sz = swz<0x1F0>(sz);

    // pass 2: phase-aligned contiguous sps broadcast. Register-only inputs —
    // runs BEFORE the barrier so no wave waits on the block's straggler.
    {
        const int F0 = 3 * s0, F1 = 3 * s1;
        const int H1 = min((F0 + 3) & ~3, F1);   // head end (first aligned pos)
        const int A1 = max(F1 & ~3, H1);         // full-chunk end
        if (j < 6) {
            const int f = (j < 3) ? (F0 + j) : (A1 + j - 3);
            const bool doit = (j < 3) ? (f < H1) : (f < F1);
            if (doit) out_sps[f] = sel3(f % 3, sx, sy, sz);
        }
        for (int f = H1 + 4 * j; f < A1; f += 64) {
            const int m = f % 3;
            const float v0 = sel3(m, sx, sy, sz);
            const float v1 = sel3(m == 2 ? 0 : m + 1, sx, sy, sz);
            const float v2 = sel3(m == 0 ? 2 : m - 1, sx, sy, sz);
            ntst4(out_sps + f, v0, v1, v2, v0);
        }
    }

    // i3/i1 reduction + LDS staging (after pass 2; only epilogue needs it)
    FUNNEL16(i3x); FUNNEL16(i3y); FUNNEL16(i3z); FUNNEL16(i1);
    if (j == 15) {
        prr[slot][0] = c;
        prr[slot][1] = i1;
        prr[slot][2] = i3x; prr[slot][3] = i3y; prr[slot][4] = i3z;
        prr[slot][5] = sx;  prr[slot][6] = sy;  prr[slot][7] = sz;
    }
    __syncthreads();

    // coalesced per-ray output stores: 256 threads, 1 float each
    {
        const int t = threadIdx.x;
        if (t < 256) {
            float val; float* addr; int ridx;
            if (t < 32)       { ridx = t;                 val = prr[ridx][0];          addr = out_bg  + r0 + t; }
            else if (t < 64)  { ridx = t - 32;            val = prr[ridx][1];          addr = out_i1  + r0 + ridx; }
            else if (t < 160) { int s = t - 64;  ridx = s / 3; val = prr[ridx][2 + s % 3]; addr = out_i3  + 3 * r0 + s; }
            else              { int s = t - 160; ridx = s / 3; val = prr[ridx][5 + s % 3]; addr = out_spr + 3 * r0 + s; }
            if (r0 + ridx < R) *addr = val;
        }
    }
}

extern "C" void kernel_launch(void* const* d_in, const int* in_sizes, int n_in,
                              void* d_out, int out_size, void* d_ws, size_t ws_size,
                              hipStream_t stream) {
    const float* alpha = (const float*)d_in[0];
    const float* v3    = (const float*)d_in[1];
    const float* v1    = (const float*)d_in[2];
    const float* w     = (const float*)d_in[3];
    const float* sv    = (const float*)d_in[4];
    const int*   rid   = (const int*)d_in[5];

    int N = in_sizes[0];
    int R = (out_size - 4 * N) / 8;  // out = N + R + 3R + R + 3R + 3N

    int* seg_se = (int*)d_ws;        // [R][2]; fully written by seg_bounds (gap-filled)

    float* out     = (float*)d_out;
    float* out_T   = out;
    float* out_bg  = out + N;
    float* out_i3  = out_bg + R;
    float* out_i1  = out_i3 + 3 * (size_t)R;
    float* out_spr = out_i1 + R;
    float* out_sps = out_spr + 3 * (size_t)R;

    const int nquad = N / 4;
    seg_bounds_kernel<<<(nquad + 255) / 256, 256, 0, stream>>>(rid, N, R, seg_se);

    // 8 waves/block, 4 rays/wave -> 32 rays per block
    int blocks = (R + 31) / 32;
    ray_kernel<<<blocks, 512, 0, stream>>>(alpha, v3, v1, w, sv, seg_se,
                                           out_T, out_bg, out_i3, out_i1, out_spr,
                                           out_sps, R);
}